// Round 1
// baseline (2638.583 us; speedup 1.0000x reference)
//
#include <hip/hip_runtime.h>
#include <hip/hip_bf16.h>
#include <math.h>

#define F 602
#define C 41
#define HP_STRIDE 48   // bf16 h row padded to 48 elems (96 B) for aligned gathers

static __device__ __forceinline__ unsigned short f2bf(float f){
  unsigned int x = __float_as_uint(f);
  x += 0x7FFFu + ((x >> 16) & 1u);   // RNE; no NaNs in this workload
  return (unsigned short)(x >> 16);
}
static __device__ __forceinline__ float bf2f(unsigned short u){
  return __uint_as_float(((unsigned int)u) << 16);
}

// edge_index may arrive as int64 (reference dtype) or int32 (harness doc).
// Detect on-device: if int64 (little-endian), all high words are 0.
__global__ void k_flag(const int* __restrict__ e32, int* __restrict__ flag){
  __shared__ int s[256];
  int t = threadIdx.x;
  int v = 0;
  for (int i = t; i < 2048; i += 256) v |= e32[2*i + 1];
  s[t] = v; __syncthreads();
  for (int off = 128; off > 0; off >>= 1){
    if (t < off) s[t] |= s[t + off];
    __syncthreads();
  }
  if (t == 0) flag[0] = (s[0] == 0) ? 1 : 0;   // 1 => int64
}

static __device__ __forceinline__ int eidx(const int* __restrict__ p, int is64, long long pos){
  return is64 ? p[2*pos] : p[pos];   // low word (values < 2^31, non-negative)
}

__global__ void k_count(const int* __restrict__ ei, const int* __restrict__ flag,
                        int* __restrict__ count, int E){
  int e = blockIdx.x * 256 + threadIdx.x;
  if (e >= E) return;
  int is64 = flag[0];
  int d = eidx(ei, is64, (long long)E + e);
  atomicAdd(&count[d], 1);
}

// block scans 2048 counts (8/thread); also computes dinv = rsqrt(indeg+1)
__global__ void k_scan1(const int* __restrict__ count, int* __restrict__ rs,
                        float* __restrict__ dinv, int* __restrict__ bsum, int N){
  __shared__ int s[256];
  int t = threadIdx.x;
  int base = blockIdx.x * 2048 + t * 8;
  int v[8]; int tot = 0;
  #pragma unroll
  for (int j = 0; j < 8; j++){
    int i = base + j;
    int c = (i < N) ? count[i] : 0;
    v[j] = c; tot += c;
    if (i < N) dinv[i] = rsqrtf((float)(c + 1));
  }
  s[t] = tot; __syncthreads();
  for (int off = 1; off < 256; off <<= 1){
    int x = (t >= off) ? s[t - off] : 0;
    __syncthreads();
    s[t] += x;
    __syncthreads();
  }
  int run = s[t] - tot;  // exclusive prefix of this thread
  #pragma unroll
  for (int j = 0; j < 8; j++){
    int i = base + j;
    if (i < N) rs[i] = run;
    run += v[j];
  }
  if (t == 255) bsum[blockIdx.x] = s[255];
}

__global__ void k_scan2(int* __restrict__ bsum, int nb){
  __shared__ int s[256];
  int t = threadIdx.x;
  int v = (t < nb) ? bsum[t] : 0;
  s[t] = v; __syncthreads();
  for (int off = 1; off < 256; off <<= 1){
    int x = (t >= off) ? s[t - off] : 0;
    __syncthreads();
    s[t] += x;
    __syncthreads();
  }
  if (t < nb) bsum[t] = s[t] - v;   // exclusive
}

__global__ void k_scan3(int* __restrict__ rs, int* __restrict__ cur,
                        const int* __restrict__ bsum, int N, int E){
  int i = blockIdx.x * 256 + threadIdx.x;
  if (i == 0) rs[N] = E;
  if (i >= N) return;
  int r = rs[i] + bsum[i >> 11];
  rs[i] = r; cur[i] = r;
}

__global__ void k_fill(const int* __restrict__ ei, const int* __restrict__ flag,
                       const float* __restrict__ dinv, int* __restrict__ cur,
                       int2* __restrict__ csr, int E){
  int e = blockIdx.x * 256 + threadIdx.x;
  if (e >= E) return;
  int is64 = flag[0];
  int s = eidx(ei, is64, e);
  int d = eidx(ei, is64, (long long)E + e);
  float norm = dinv[s] * dinv[d];
  int pos = atomicAdd(&cur[d], 1);
  csr[pos] = make_int2(s, __float_as_int(norm));
}

// h = x @ W, fp32 compute, bf16 output (padded rows). One thread per row,
// x staged through LDS for coalescing; W reads are wave-uniform -> s_load.
__global__ __launch_bounds__(256) void k_gemm(const float* __restrict__ x,
        const float* __restrict__ W, unsigned short* __restrict__ hp, int N){
  __shared__ float tile[256][17];   // +1 pad: conflict-free column reads
  int t = threadIdx.x;
  int rb0 = blockIdx.x * 256;
  int row = rb0 + t;
  float acc[C];
  #pragma unroll
  for (int c = 0; c < C; c++) acc[c] = 0.f;
  int tr = t >> 4, tc = t & 15;
  for (int c0 = 0; c0 < F; c0 += 16){
    int kmax = F - c0; if (kmax > 16) kmax = 16;
    __syncthreads();
    if (tc < kmax){
      #pragma unroll
      for (int i = 0; i < 16; i++){
        int r = tr + i * 16;
        int gr = rb0 + r;
        if (gr < N) tile[r][tc] = x[(long long)gr * F + c0 + tc];
      }
    }
    __syncthreads();
    if (row < N){
      if (kmax == 16){
        #pragma unroll
        for (int k = 0; k < 16; k++){
          float xk = tile[t][k];
          const float* Wr = W + (c0 + k) * C;
          #pragma unroll
          for (int c = 0; c < C; c++) acc[c] = fmaf(xk, Wr[c], acc[c]);
        }
      } else {
        for (int k = 0; k < kmax; k++){
          float xk = tile[t][k];
          const float* Wr = W + (c0 + k) * C;
          #pragma unroll
          for (int c = 0; c < C; c++) acc[c] = fmaf(xk, Wr[c], acc[c]);
        }
      }
    }
  }
  if (row < N){
    unsigned int* hp32 = (unsigned int*)(hp + (long long)row * HP_STRIDE);
    #pragma unroll
    for (int c = 0; c < 20; c++){
      unsigned int lo = f2bf(acc[2*c]);
      unsigned int hi = f2bf(acc[2*c + 1]);
      hp32[c] = lo | (hi << 16);
    }
    hp[(long long)row * HP_STRIDE + 40] = f2bf(acc[40]);
  }
}

// one wave per node; lanes 0..40 = classes. Gather h[src] rows, fp32 accumulate.
__global__ __launch_bounds__(256) void k_agg(const unsigned short* __restrict__ hp,
        const int2* __restrict__ csr, const int* __restrict__ rs,
        const float* __restrict__ dinv, const float* __restrict__ b,
        float* __restrict__ agg, int N){
  int node = blockIdx.x * 4 + (threadIdx.x >> 6);
  int lane = threadIdx.x & 63;
  if (node >= N) return;
  int beg = rs[node], end = rs[node + 1];
  float dn = dinv[node];
  bool act = lane < C;
  float acc = 0.f;
  if (act) acc = dn * dn * bf2f(hp[(long long)node * HP_STRIDE + lane]);  // self-loop
  int i = beg;
  for (; i + 1 < end; i += 2){
    int2 e0 = csr[i], e1 = csr[i + 1];
    float h0 = 0.f, h1 = 0.f;
    if (act){
      h0 = bf2f(hp[(long long)e0.x * HP_STRIDE + lane]);
      h1 = bf2f(hp[(long long)e1.x * HP_STRIDE + lane]);
    }
    acc = fmaf(__int_as_float(e0.y), h0, acc);
    acc = fmaf(__int_as_float(e1.y), h1, acc);
  }
  if (i < end){
    int2 e0 = csr[i];
    if (act) acc = fmaf(__int_as_float(e0.y),
                        bf2f(hp[(long long)e0.x * HP_STRIDE + lane]), acc);
  }
  if (act) agg[(long long)node * C + lane] = acc + b[lane];
}

__global__ __launch_bounds__(256) void k_lsm(const float* __restrict__ agg,
        float* __restrict__ z, int N){
  int node = blockIdx.x * 4 + (threadIdx.x >> 6);
  int lane = threadIdx.x & 63;
  if (node >= N) return;
  bool act = lane < C;
  float a = act ? agg[(long long)node * C + lane] : -3.0e38f;
  float m = a;
  #pragma unroll
  for (int off = 32; off > 0; off >>= 1) m = fmaxf(m, __shfl_xor(m, off, 64));
  float ex = act ? expf(a - m) : 0.f;
  float s = ex;
  #pragma unroll
  for (int off = 32; off > 0; off >>= 1) s += __shfl_xor(s, off, 64);
  if (act) z[(long long)node * C + lane] = a - m - logf(s);
}

extern "C" void kernel_launch(void* const* d_in, const int* in_sizes, int n_in,
                              void* d_out, int out_size, void* d_ws, size_t ws_size,
                              hipStream_t stream){
  const float* x = (const float*)d_in[0];
  const float* W = (const float*)d_in[1];
  const float* b = (const float*)d_in[2];
  const int*   ei = (const int*)d_in[3];
  int N = in_sizes[0] / F;   // 200000
  int E = in_sizes[3] / 2;   // 3200000 (element count is dtype-independent)

  float* out = (float*)d_out;
  float* agg = out;
  float* z   = out + (long long)N * C;
  // bf16 h table lives in the z region (N*48*2 = 19.2MB <= N*41*4 = 32.8MB);
  // z is written only after aggregation has consumed h.
  unsigned short* hp = (unsigned short*)z;

  char* ws = (char*)d_ws;
  auto al = [](size_t v){ return (v + 255) & ~size_t(255); };
  size_t o = 0;
  int*   flag  = (int*)(ws + o);  o = al(o + 4);
  int*   count = (int*)(ws + o);  o = al(o + (size_t)N * 4);
  float* dinv  = (float*)(ws + o); o = al(o + (size_t)N * 4);
  int*   rs    = (int*)(ws + o);  o = al(o + ((size_t)N + 1) * 4);
  int*   cur   = (int*)(ws + o);  o = al(o + (size_t)N * 4);
  int*   bsum  = (int*)(ws + o);  o = al(o + 4096);
  int2*  csr   = (int2*)(ws + o); o = al(o + (size_t)E * 8);

  int nb_e    = (E + 255) / 256;
  int nb_scan = (N + 2047) / 2048;
  int nb_n    = (N + 255) / 256;
  int nb_node = (N + 3) / 4;

  k_flag<<<1, 256, 0, stream>>>(ei, flag);
  hipMemsetAsync(count, 0, (size_t)N * 4, stream);
  k_count<<<nb_e, 256, 0, stream>>>(ei, flag, count, E);
  k_scan1<<<nb_scan, 256, 0, stream>>>(count, rs, dinv, bsum, N);
  k_scan2<<<1, 256, 0, stream>>>(bsum, nb_scan);
  k_scan3<<<nb_n, 256, 0, stream>>>(rs, cur, bsum, N, E);
  k_fill<<<nb_e, 256, 0, stream>>>(ei, flag, dinv, cur, csr, E);
  k_gemm<<<nb_n, 256, 0, stream>>>(x, W, hp, N);
  k_agg<<<nb_node, 256, 0, stream>>>(hp, csr, rs, dinv, b, agg, N);
  k_lsm<<<nb_node, 256, 0, stream>>>(agg, z, N);
}

// Round 2
// 1429.992 us; speedup vs baseline: 1.8452x; 1.8452x over previous
//
#include <hip/hip_runtime.h>
#include <hip/hip_bf16.h>
#include <math.h>

#define F 602
#define C 41
#define HP_STRIDE 48   // bf16 h row padded to 48 elems (96 B) for aligned gathers
#define KSTEPS 19      // ceil(602/32)

typedef short short8 __attribute__((ext_vector_type(8)));
typedef float f32x4 __attribute__((ext_vector_type(4)));

static __device__ __forceinline__ unsigned short f2bf(float f){
  unsigned int x = __float_as_uint(f);
  x += 0x7FFFu + ((x >> 16) & 1u);   // RNE; no NaNs in this workload
  return (unsigned short)(x >> 16);
}
static __device__ __forceinline__ float bf2f(unsigned short u){
  return __uint_as_float(((unsigned int)u) << 16);
}

// edge_index may arrive as int64 (reference dtype) or int32 (harness doc).
// Detect on-device: if int64 (little-endian), all high words are 0.
__global__ void k_flag(const int* __restrict__ e32, int* __restrict__ flag){
  __shared__ int s[256];
  int t = threadIdx.x;
  int v = 0;
  for (int i = t; i < 2048; i += 256) v |= e32[2*i + 1];
  s[t] = v; __syncthreads();
  for (int off = 128; off > 0; off >>= 1){
    if (t < off) s[t] |= s[t + off];
    __syncthreads();
  }
  if (t == 0) flag[0] = (s[0] == 0) ? 1 : 0;   // 1 => int64
}

static __device__ __forceinline__ int eidx(const int* __restrict__ p, int is64, long long pos){
  return is64 ? p[2*pos] : p[pos];   // low word (values < 2^31, non-negative)
}

__global__ void k_count(const int* __restrict__ ei, const int* __restrict__ flag,
                        int* __restrict__ count, int E){
  int e = blockIdx.x * 256 + threadIdx.x;
  if (e >= E) return;
  int is64 = flag[0];
  int d = eidx(ei, is64, (long long)E + e);
  atomicAdd(&count[d], 1);
}

// block scans 2048 counts (8/thread); also computes dinv = rsqrt(indeg+1)
__global__ void k_scan1(const int* __restrict__ count, int* __restrict__ rs,
                        float* __restrict__ dinv, int* __restrict__ bsum, int N){
  __shared__ int s[256];
  int t = threadIdx.x;
  int base = blockIdx.x * 2048 + t * 8;
  int v[8]; int tot = 0;
  #pragma unroll
  for (int j = 0; j < 8; j++){
    int i = base + j;
    int c = (i < N) ? count[i] : 0;
    v[j] = c; tot += c;
    if (i < N) dinv[i] = rsqrtf((float)(c + 1));
  }
  s[t] = tot; __syncthreads();
  for (int off = 1; off < 256; off <<= 1){
    int x = (t >= off) ? s[t - off] : 0;
    __syncthreads();
    s[t] += x;
    __syncthreads();
  }
  int run = s[t] - tot;  // exclusive prefix of this thread
  #pragma unroll
  for (int j = 0; j < 8; j++){
    int i = base + j;
    if (i < N) rs[i] = run;
    run += v[j];
  }
  if (t == 255) bsum[blockIdx.x] = s[255];
}

__global__ void k_scan2(int* __restrict__ bsum, int nb){
  __shared__ int s[256];
  int t = threadIdx.x;
  int v = (t < nb) ? bsum[t] : 0;
  s[t] = v; __syncthreads();
  for (int off = 1; off < 256; off <<= 1){
    int x = (t >= off) ? s[t - off] : 0;
    __syncthreads();
    s[t] += x;
    __syncthreads();
  }
  if (t < nb) bsum[t] = s[t] - v;   // exclusive
}

__global__ void k_scan3(int* __restrict__ rs, int* __restrict__ cur,
                        const int* __restrict__ bsum, int N, int E){
  int i = blockIdx.x * 256 + threadIdx.x;
  if (i == 0) rs[N] = E;
  if (i >= N) return;
  int r = rs[i] + bsum[i >> 11];
  rs[i] = r; cur[i] = r;
}

__global__ void k_fill(const int* __restrict__ ei, const int* __restrict__ flag,
                       const float* __restrict__ dinv, int* __restrict__ cur,
                       int2* __restrict__ csr, int E){
  int e = blockIdx.x * 256 + threadIdx.x;
  if (e >= E) return;
  int is64 = flag[0];
  int s = eidx(ei, is64, e);
  int d = eidx(ei, is64, (long long)E + e);
  float norm = dinv[s] * dinv[d];
  int pos = atomicAdd(&cur[d], 1);
  csr[pos] = make_int2(s, __float_as_int(norm));
}

// Pre-swizzle W (fp32 [602][41]) into bf16 B-fragment layout for
// mfma_f32_16x16x32_bf16: Wf[((s*3+nt)*64+lane)*8 + j] = W[k=s*32+quad*8+j][n=nt*16+l16]
__global__ void k_wprep(const float* __restrict__ W, unsigned short* __restrict__ Wf){
  int idx = blockIdx.x * 256 + threadIdx.x;
  if (idx >= KSTEPS * 3 * 64) return;
  int lane = idx & 63;
  int nt = (idx >> 6) % 3;
  int s = idx / (3 * 64);
  int quad = lane >> 4, l16 = lane & 15;
  int n = nt * 16 + l16;
  unsigned int w[4];
  #pragma unroll
  for (int p = 0; p < 4; p++){
    int k0 = s * 32 + quad * 8 + 2 * p;
    float lo = (k0     < F && n < C) ? W[k0 * C + n]       : 0.f;
    float hi = (k0 + 1 < F && n < C) ? W[(k0 + 1) * C + n] : 0.f;
    w[p] = (unsigned)f2bf(lo) | ((unsigned)f2bf(hi) << 16);
  }
  ((uint4*)Wf)[idx] = make_uint4(w[0], w[1], w[2], w[3]);
}

// MFMA GEMM: h = x @ W -> bf16 padded rows hp. Block = 256 thr (4 waves),
// 128 rows/block; wave owns 32 rows x 48 cols (2 M-tiles x 3 N-tiles).
// A staged fp32->bf16 in LDS ([128][40] ushort, +8 pad => conflict-light),
// B-frags straight from the pre-swizzled 58 KB table (L1/L2 resident).
__global__ __launch_bounds__(256) void k_gemm2(const float* __restrict__ x,
        const unsigned short* __restrict__ Wf, unsigned short* __restrict__ hp, int N){
  __shared__ unsigned short As[128 * 40];
  const int t = threadIdx.x;
  const int rb0 = blockIdx.x * 128;
  // staging role: 2 threads per row, 16 floats each
  const int sr = t >> 1, half = t & 1;
  const long long grow_s = rb0 + sr;
  const bool vrow = grow_s < N;
  const float* xr = x + grow_s * (long long)F;
  // mfma role
  const int wv = t >> 6, lane = t & 63;
  const int quad = lane >> 4, l16 = lane & 15;
  const int arow0 = (wv * 32 + l16) * 40 + quad * 8;  // ushort index, m-tile 0
  const int arow1 = arow0 + 16 * 40;                  // m-tile 1
  const short8* wf8 = (const short8*)Wf;

  f32x4 acc[2][3];
  #pragma unroll
  for (int m = 0; m < 2; m++)
    #pragma unroll
    for (int nt = 0; nt < 3; nt++) acc[m][nt] = (f32x4){0.f, 0.f, 0.f, 0.f};

  float2 v[8];
  {
    int k0 = half * 16;
    #pragma unroll
    for (int q = 0; q < 8; q++){
      int k = k0 + 2 * q;
      v[q] = (vrow && k < F) ? *(const float2*)(xr + k) : make_float2(0.f, 0.f);
    }
  }
  for (int s = 0; s < KSTEPS; s++){
    unsigned int w[8];
    #pragma unroll
    for (int q = 0; q < 8; q++)
      w[q] = (unsigned)f2bf(v[q].x) | ((unsigned)f2bf(v[q].y) << 16);
    __syncthreads();   // previous iter's A-frag reads complete
    {
      int base = sr * 40 + half * 16;
      *((uint4*)&As[base])     = make_uint4(w[0], w[1], w[2], w[3]);
      *((uint4*)&As[base + 8]) = make_uint4(w[4], w[5], w[6], w[7]);
    }
    if (s + 1 < KSTEPS){   // prefetch next tile while MFMA runs
      int k0 = (s + 1) * 32 + half * 16;
      #pragma unroll
      for (int q = 0; q < 8; q++){
        int k = k0 + 2 * q;
        v[q] = (vrow && k < F) ? *(const float2*)(xr + k) : make_float2(0.f, 0.f);
      }
    }
    __syncthreads();
    short8 b0 = wf8[(s * 3 + 0) * 64 + lane];
    short8 b1 = wf8[(s * 3 + 1) * 64 + lane];
    short8 b2 = wf8[(s * 3 + 2) * 64 + lane];
    short8 a0 = *(const short8*)&As[arow0];
    short8 a1 = *(const short8*)&As[arow1];
    acc[0][0] = __builtin_amdgcn_mfma_f32_16x16x32_bf16(a0, b0, acc[0][0], 0, 0, 0);
    acc[0][1] = __builtin_amdgcn_mfma_f32_16x16x32_bf16(a0, b1, acc[0][1], 0, 0, 0);
    acc[0][2] = __builtin_amdgcn_mfma_f32_16x16x32_bf16(a0, b2, acc[0][2], 0, 0, 0);
    acc[1][0] = __builtin_amdgcn_mfma_f32_16x16x32_bf16(a1, b0, acc[1][0], 0, 0, 0);
    acc[1][1] = __builtin_amdgcn_mfma_f32_16x16x32_bf16(a1, b1, acc[1][1], 0, 0, 0);
    acc[1][2] = __builtin_amdgcn_mfma_f32_16x16x32_bf16(a1, b2, acc[1][2], 0, 0, 0);
  }
  // epilogue: C/D layout col=lane&15, row=quad*4+reg  [m89-verified]
  #pragma unroll
  for (int m = 0; m < 2; m++){
    int rl = wv * 32 + m * 16 + quad * 4;
    #pragma unroll
    for (int reg = 0; reg < 4; reg++){
      long long grow = rb0 + rl + reg;
      if (grow < N){
        unsigned short* hr = hp + grow * HP_STRIDE;
        hr[0 * 16 + l16] = f2bf(acc[m][0][reg]);
        hr[1 * 16 + l16] = f2bf(acc[m][1][reg]);
        hr[2 * 16 + l16] = f2bf(acc[m][2][reg]);
      }
    }
  }
}

// one wave per node; lanes 0..40 = classes. Gather h[src] rows, fp32 accumulate.
__global__ __launch_bounds__(256) void k_agg(const unsigned short* __restrict__ hp,
        const int2* __restrict__ csr, const int* __restrict__ rs,
        const float* __restrict__ dinv, const float* __restrict__ b,
        float* __restrict__ agg, int N){
  int node = blockIdx.x * 4 + (threadIdx.x >> 6);
  int lane = threadIdx.x & 63;
  if (node >= N) return;
  int beg = rs[node], end = rs[node + 1];
  float dn = dinv[node];
  bool act = lane < C;
  float acc = 0.f;
  if (act) acc = dn * dn * bf2f(hp[(long long)node * HP_STRIDE + lane]);  // self-loop
  int i = beg;
  for (; i + 1 < end; i += 2){
    int2 e0 = csr[i], e1 = csr[i + 1];
    float h0 = 0.f, h1 = 0.f;
    if (act){
      h0 = bf2f(hp[(long long)e0.x * HP_STRIDE + lane]);
      h1 = bf2f(hp[(long long)e1.x * HP_STRIDE + lane]);
    }
    acc = fmaf(__int_as_float(e0.y), h0, acc);
    acc = fmaf(__int_as_float(e1.y), h1, acc);
  }
  if (i < end){
    int2 e0 = csr[i];
    if (act) acc = fmaf(__int_as_float(e0.y),
                        bf2f(hp[(long long)e0.x * HP_STRIDE + lane]), acc);
  }
  if (act) agg[(long long)node * C + lane] = acc + b[lane];
}

__global__ __launch_bounds__(256) void k_lsm(const float* __restrict__ agg,
        float* __restrict__ z, int N){
  int node = blockIdx.x * 4 + (threadIdx.x >> 6);
  int lane = threadIdx.x & 63;
  if (node >= N) return;
  bool act = lane < C;
  float a = act ? agg[(long long)node * C + lane] : -3.0e38f;
  float m = a;
  #pragma unroll
  for (int off = 32; off > 0; off >>= 1) m = fmaxf(m, __shfl_xor(m, off, 64));
  float ex = act ? expf(a - m) : 0.f;
  float s = ex;
  #pragma unroll
  for (int off = 32; off > 0; off >>= 1) s += __shfl_xor(s, off, 64);
  if (act) z[(long long)node * C + lane] = a - m - logf(s);
}

extern "C" void kernel_launch(void* const* d_in, const int* in_sizes, int n_in,
                              void* d_out, int out_size, void* d_ws, size_t ws_size,
                              hipStream_t stream){
  const float* x = (const float*)d_in[0];
  const float* W = (const float*)d_in[1];
  const float* b = (const float*)d_in[2];
  const int*   ei = (const int*)d_in[3];
  int N = in_sizes[0] / F;   // 200000
  int E = in_sizes[3] / 2;   // 3200000

  float* out = (float*)d_out;
  float* agg = out;
  float* z   = out + (long long)N * C;
  // bf16 h table lives in the z region (N*48*2 = 19.2MB <= N*41*4 = 32.8MB);
  // z is written only after aggregation has consumed h.
  unsigned short* hp = (unsigned short*)z;

  char* ws = (char*)d_ws;
  auto al = [](size_t v){ return (v + 255) & ~size_t(255); };
  size_t o = 0;
  int*   flag  = (int*)(ws + o);  o = al(o + 4);
  int*   count = (int*)(ws + o);  o = al(o + (size_t)N * 4);
  float* dinv  = (float*)(ws + o); o = al(o + (size_t)N * 4);
  int*   rs    = (int*)(ws + o);  o = al(o + ((size_t)N + 1) * 4);
  int*   cur   = (int*)(ws + o);  o = al(o + (size_t)N * 4);
  int*   bsum  = (int*)(ws + o);  o = al(o + 4096);
  unsigned short* Wf = (unsigned short*)(ws + o); o = al(o + (size_t)KSTEPS * 3 * 64 * 16);
  int2*  csr   = (int2*)(ws + o); o = al(o + (size_t)E * 8);

  int nb_e    = (E + 255) / 256;
  int nb_scan = (N + 2047) / 2048;
  int nb_n    = (N + 255) / 256;
  int nb_g    = (N + 127) / 128;
  int nb_node = (N + 3) / 4;
  int nb_w    = (KSTEPS * 3 * 64 + 255) / 256;

  k_flag<<<1, 256, 0, stream>>>(ei, flag);
  hipMemsetAsync(count, 0, (size_t)N * 4, stream);
  k_count<<<nb_e, 256, 0, stream>>>(ei, flag, count, E);
  k_wprep<<<nb_w, 256, 0, stream>>>(W, Wf);
  k_scan1<<<nb_scan, 256, 0, stream>>>(count, rs, dinv, bsum, N);
  k_scan2<<<1, 256, 0, stream>>>(bsum, nb_scan);
  k_scan3<<<nb_n, 256, 0, stream>>>(rs, cur, bsum, N, E);
  k_fill<<<nb_e, 256, 0, stream>>>(ei, flag, dinv, cur, csr, E);
  k_gemm2<<<nb_g, 256, 0, stream>>>(x, Wf, hp, N);
  k_agg<<<nb_node, 256, 0, stream>>>(hp, csr, rs, dinv, b, agg, N);
  k_lsm<<<nb_node, 256, 0, stream>>>(agg, z, N);
}

// Round 3
// 1304.107 us; speedup vs baseline: 2.0233x; 1.0965x over previous
//
#include <hip/hip_runtime.h>
#include <hip/hip_bf16.h>
#include <math.h>

#define F 602
#define C 41
#define HP_STRIDE 48   // bf16 h row padded to 48 elems (96 B) for aligned gathers
#define KSTEPS 19      // ceil(602/32)
#define GROWS 64       // gemm rows per block
#define ASTRIDE 616    // LDS row stride in u16: 308 dwords -> 20 mod 32 -> 2-way (free)

typedef short short8 __attribute__((ext_vector_type(8)));
typedef float f32x4 __attribute__((ext_vector_type(4)));

static __device__ __forceinline__ unsigned short f2bf(float f){
  unsigned int x = __float_as_uint(f);
  x += 0x7FFFu + ((x >> 16) & 1u);   // RNE; no NaNs in this workload
  return (unsigned short)(x >> 16);
}
static __device__ __forceinline__ float bf2f(unsigned short u){
  return __uint_as_float(((unsigned int)u) << 16);
}

// edge_index may arrive as int64 (reference dtype) or int32 (harness doc).
// Detect on-device: if int64 (little-endian), all high words are 0.
__global__ void k_flag(const int* __restrict__ e32, int* __restrict__ flag){
  __shared__ int s[256];
  int t = threadIdx.x;
  int v = 0;
  for (int i = t; i < 2048; i += 256) v |= e32[2*i + 1];
  s[t] = v; __syncthreads();
  for (int off = 128; off > 0; off >>= 1){
    if (t < off) s[t] |= s[t + off];
    __syncthreads();
  }
  if (t == 0) flag[0] = (s[0] == 0) ? 1 : 0;   // 1 => int64
}

static __device__ __forceinline__ int eidx(const int* __restrict__ p, int is64, long long pos){
  return is64 ? p[2*pos] : p[pos];   // low word (values < 2^31, non-negative)
}

__global__ void k_count(const int* __restrict__ ei, const int* __restrict__ flag,
                        int* __restrict__ count, int E){
  int e = blockIdx.x * 256 + threadIdx.x;
  if (e >= E) return;
  int is64 = flag[0];
  int d = eidx(ei, is64, (long long)E + e);
  atomicAdd(&count[d], 1);
}

// block scans 2048 counts (8/thread); also computes dinv = rsqrt(indeg+1)
__global__ void k_scan1(const int* __restrict__ count, int* __restrict__ rs,
                        float* __restrict__ dinv, int* __restrict__ bsum, int N){
  __shared__ int s[256];
  int t = threadIdx.x;
  int base = blockIdx.x * 2048 + t * 8;
  int v[8]; int tot = 0;
  #pragma unroll
  for (int j = 0; j < 8; j++){
    int i = base + j;
    int c = (i < N) ? count[i] : 0;
    v[j] = c; tot += c;
    if (i < N) dinv[i] = rsqrtf((float)(c + 1));
  }
  s[t] = tot; __syncthreads();
  for (int off = 1; off < 256; off <<= 1){
    int x = (t >= off) ? s[t - off] : 0;
    __syncthreads();
    s[t] += x;
    __syncthreads();
  }
  int run = s[t] - tot;  // exclusive prefix of this thread
  #pragma unroll
  for (int j = 0; j < 8; j++){
    int i = base + j;
    if (i < N) rs[i] = run;
    run += v[j];
  }
  if (t == 255) bsum[blockIdx.x] = s[255];
}

__global__ void k_scan2(int* __restrict__ bsum, int nb){
  __shared__ int s[256];
  int t = threadIdx.x;
  int v = (t < nb) ? bsum[t] : 0;
  s[t] = v; __syncthreads();
  for (int off = 1; off < 256; off <<= 1){
    int x = (t >= off) ? s[t - off] : 0;
    __syncthreads();
    s[t] += x;
    __syncthreads();
  }
  if (t < nb) bsum[t] = s[t] - v;   // exclusive
}

__global__ void k_scan3(int* __restrict__ rs, int* __restrict__ cur,
                        const int* __restrict__ bsum, int N, int E){
  int i = blockIdx.x * 256 + threadIdx.x;
  if (i == 0) rs[N] = E;
  if (i >= N) return;
  int r = rs[i] + bsum[i >> 11];
  rs[i] = r; cur[i] = r;
}

// csr holds src only (4 B/edge); norm recomputed in k_agg from dinv.
__global__ void k_fill(const int* __restrict__ ei, const int* __restrict__ flag,
                       int* __restrict__ cur, int* __restrict__ csr, int E){
  int e = blockIdx.x * 256 + threadIdx.x;
  if (e >= E) return;
  int is64 = flag[0];
  int s = eidx(ei, is64, e);
  int d = eidx(ei, is64, (long long)E + e);
  int pos = atomicAdd(&cur[d], 1);
  csr[pos] = s;
}

// Pre-swizzle W (fp32 [602][41]) into bf16 B-fragment layout for
// mfma_f32_16x16x32_bf16: Wf[((s*3+nt)*64+lane)*8 + j] = W[k=s*32+quad*8+j][n=nt*16+l16]
__global__ void k_wprep(const float* __restrict__ W, unsigned short* __restrict__ Wf){
  int idx = blockIdx.x * 256 + threadIdx.x;
  if (idx >= KSTEPS * 3 * 64) return;
  int lane = idx & 63;
  int nt = (idx >> 6) % 3;
  int s = idx / (3 * 64);
  int quad = lane >> 4, l16 = lane & 15;
  int n = nt * 16 + l16;
  unsigned int w[4];
  #pragma unroll
  for (int p = 0; p < 4; p++){
    int k0 = s * 32 + quad * 8 + 2 * p;
    float lo = (k0     < F && n < C) ? W[k0 * C + n]       : 0.f;
    float hi = (k0 + 1 < F && n < C) ? W[(k0 + 1) * C + n] : 0.f;
    w[p] = (unsigned)f2bf(lo) | ((unsigned)f2bf(hi) << 16);
  }
  ((uint4*)Wf)[idx] = make_uint4(w[0], w[1], w[2], w[3]);
}

// MFMA GEMM v3: stage the ENTIRE contiguous 64-row x-tile (154 KB) into LDS
// with flat coalesced float4 loads, ONE barrier, then 19 MFMA K-steps from LDS.
// Wave w owns 16 rows x 48 cols (3 N-tiles). W-frags from the 58 KB L1-hot table.
__global__ __launch_bounds__(256) void k_gemm3(const float* __restrict__ x,
        const unsigned short* __restrict__ Wf, unsigned short* __restrict__ hp, int N){
  __shared__ unsigned short As[GROWS * ASTRIDE];
  const int t = threadIdx.x;
  const long long rb0 = (long long)blockIdx.x * GROWS;
  // ---- zero the K-tail (cols 602..607 feed the s=18 MFMA; must not be NaN) ----
  for (int i = t; i < GROWS * 6; i += 256){
    int r = i / 6, c = 602 + (i - r * 6);
    As[r * ASTRIDE + c] = 0;
  }
  // ---- stage: flat coalesced float4 over the contiguous tile ----
  long long nrow = (long long)N - rb0; if (nrow > GROWS) nrow = GROWS;
  const int limit = (int)(nrow * F);              // floats in tile (38528 full)
  const float* base = x + rb0 * F;                // 16B-aligned (rb0 even)
  #pragma unroll 4
  for (int f4 = t; f4 * 4 < limit; f4 += 256){
    int idx = f4 * 4;
    float4 v = *(const float4*)(base + idx);
    int row = idx / F;                            // magic-mul division
    int col = idx - row * F;
    if (col <= F - 4){                            // fast path: single row
      int a = row * ASTRIDE + col;                // col even -> a even
      unsigned p0 = (unsigned)f2bf(v.x) | ((unsigned)f2bf(v.y) << 16);
      unsigned p1 = (unsigned)f2bf(v.z) | ((unsigned)f2bf(v.w) << 16);
      *(unsigned*)&As[a]     = p0;
      *(unsigned*)&As[a + 2] = p1;
    } else {                                      // straddles a row boundary
      float e[4] = {v.x, v.y, v.z, v.w};
      #pragma unroll
      for (int q = 0; q < 4; q++){
        int ii = idx + q;
        int r2 = ii / F, c2 = ii - r2 * F;
        As[r2 * ASTRIDE + c2] = f2bf(e[q]);
      }
    }
  }
  __syncthreads();
  // ---- compute: wave w -> rows [w*16, w*16+16), 3 N-tiles, 19 K-steps ----
  const int wv = t >> 6, lane = t & 63;
  const int quad = lane >> 4, l16 = lane & 15;
  const unsigned short* arow = &As[(wv * 16 + l16) * ASTRIDE + quad * 8];
  const short8* wf8 = (const short8*)Wf;
  f32x4 acc0 = {0.f,0.f,0.f,0.f}, acc1 = acc0, acc2 = acc0;
  #pragma unroll
  for (int s = 0; s < KSTEPS; s++){
    short8 a  = *(const short8*)(arow + s * 32);
    short8 b0 = wf8[(s * 3 + 0) * 64 + lane];
    short8 b1 = wf8[(s * 3 + 1) * 64 + lane];
    short8 b2 = wf8[(s * 3 + 2) * 64 + lane];
    acc0 = __builtin_amdgcn_mfma_f32_16x16x32_bf16(a, b0, acc0, 0, 0, 0);
    acc1 = __builtin_amdgcn_mfma_f32_16x16x32_bf16(a, b1, acc1, 0, 0, 0);
    acc2 = __builtin_amdgcn_mfma_f32_16x16x32_bf16(a, b2, acc2, 0, 0, 0);
  }
  // epilogue: C/D layout col=lane&15, row=quad*4+reg  [m89-verified]
  int rl = wv * 16 + quad * 4;
  #pragma unroll
  for (int reg = 0; reg < 4; reg++){
    long long grow = rb0 + rl + reg;
    if (grow < N){
      unsigned short* hr = hp + grow * HP_STRIDE;
      hr[0 * 16 + l16] = f2bf(acc0[reg]);
      hr[1 * 16 + l16] = f2bf(acc1[reg]);
      hr[2 * 16 + l16] = f2bf(acc2[reg]);
    }
  }
}

// one wave per node; lanes 0..40 = classes. Gather h[src] rows, fp32 accumulate.
// norm = dinv[src]*dinv[dst] recomputed here (dinv is 800 KB, L2-resident).
__global__ __launch_bounds__(256) void k_agg(const unsigned short* __restrict__ hp,
        const int* __restrict__ csr, const int* __restrict__ rs,
        const float* __restrict__ dinv, const float* __restrict__ b,
        float* __restrict__ agg, int N){
  int node = blockIdx.x * 4 + (threadIdx.x >> 6);
  int lane = threadIdx.x & 63;
  if (node >= N) return;
  int beg = rs[node], end = rs[node + 1];
  float dn = dinv[node];
  bool act = lane < C;
  float acc = 0.f;
  if (act) acc = dn * dn * bf2f(hp[(long long)node * HP_STRIDE + lane]);  // self-loop
  int i = beg;
  for (; i + 3 < end; i += 4){
    int s0 = csr[i], s1 = csr[i+1], s2 = csr[i+2], s3 = csr[i+3];
    float n0 = dinv[s0] * dn, n1 = dinv[s1] * dn;
    float n2 = dinv[s2] * dn, n3 = dinv[s3] * dn;
    float h0 = 0.f, h1 = 0.f, h2 = 0.f, h3 = 0.f;
    if (act){
      h0 = bf2f(hp[(long long)s0 * HP_STRIDE + lane]);
      h1 = bf2f(hp[(long long)s1 * HP_STRIDE + lane]);
      h2 = bf2f(hp[(long long)s2 * HP_STRIDE + lane]);
      h3 = bf2f(hp[(long long)s3 * HP_STRIDE + lane]);
    }
    acc = fmaf(n0, h0, acc); acc = fmaf(n1, h1, acc);
    acc = fmaf(n2, h2, acc); acc = fmaf(n3, h3, acc);
  }
  for (; i < end; i++){
    int s0 = csr[i];
    float n0 = dinv[s0] * dn;
    if (act) acc = fmaf(n0, bf2f(hp[(long long)s0 * HP_STRIDE + lane]), acc);
  }
  if (act) agg[(long long)node * C + lane] = acc + b[lane];
}

__global__ __launch_bounds__(256) void k_lsm(const float* __restrict__ agg,
        float* __restrict__ z, int N){
  int node = blockIdx.x * 4 + (threadIdx.x >> 6);
  int lane = threadIdx.x & 63;
  if (node >= N) return;
  bool act = lane < C;
  float a = act ? agg[(long long)node * C + lane] : -3.0e38f;
  float m = a;
  #pragma unroll
  for (int off = 32; off > 0; off >>= 1) m = fmaxf(m, __shfl_xor(m, off, 64));
  float ex = act ? expf(a - m) : 0.f;
  float s = ex;
  #pragma unroll
  for (int off = 32; off > 0; off >>= 1) s += __shfl_xor(s, off, 64);
  if (act) z[(long long)node * C + lane] = a - m - logf(s);
}

extern "C" void kernel_launch(void* const* d_in, const int* in_sizes, int n_in,
                              void* d_out, int out_size, void* d_ws, size_t ws_size,
                              hipStream_t stream){
  const float* x = (const float*)d_in[0];
  const float* W = (const float*)d_in[1];
  const float* b = (const float*)d_in[2];
  const int*   ei = (const int*)d_in[3];
  int N = in_sizes[0] / F;   // 200000
  int E = in_sizes[3] / 2;   // 3200000

  float* out = (float*)d_out;
  float* agg = out;
  float* z   = out + (long long)N * C;
  // bf16 h table lives in the z region (N*48*2 = 19.2MB <= N*41*4 = 32.8MB);
  // z is written only after aggregation has consumed h.
  unsigned short* hp = (unsigned short*)z;

  char* ws = (char*)d_ws;
  auto al = [](size_t v){ return (v + 255) & ~size_t(255); };
  size_t o = 0;
  int*   flag  = (int*)(ws + o);  o = al(o + 4);
  int*   count = (int*)(ws + o);  o = al(o + (size_t)N * 4);
  float* dinv  = (float*)(ws + o); o = al(o + (size_t)N * 4);
  int*   rs    = (int*)(ws + o);  o = al(o + ((size_t)N + 1) * 4);
  int*   cur   = (int*)(ws + o);  o = al(o + (size_t)N * 4);
  int*   bsum  = (int*)(ws + o);  o = al(o + 4096);
  unsigned short* Wf = (unsigned short*)(ws + o); o = al(o + (size_t)KSTEPS * 3 * 64 * 16);
  int*   csr   = (int*)(ws + o);  o = al(o + (size_t)E * 4);

  int nb_e    = (E + 255) / 256;
  int nb_scan = (N + 2047) / 2048;
  int nb_n    = (N + 255) / 256;
  int nb_g    = (N + GROWS - 1) / GROWS;
  int nb_node = (N + 3) / 4;
  int nb_w    = (KSTEPS * 3 * 64 + 255) / 256;

  k_flag<<<1, 256, 0, stream>>>(ei, flag);
  hipMemsetAsync(count, 0, (size_t)N * 4, stream);
  k_count<<<nb_e, 256, 0, stream>>>(ei, flag, count, E);
  k_wprep<<<nb_w, 256, 0, stream>>>(W, Wf);
  k_scan1<<<nb_scan, 256, 0, stream>>>(count, rs, dinv, bsum, N);
  k_scan2<<<1, 256, 0, stream>>>(bsum, nb_scan);
  k_scan3<<<nb_n, 256, 0, stream>>>(rs, cur, bsum, N, E);
  k_fill<<<nb_e, 256, 0, stream>>>(ei, flag, cur, csr, E);
  k_gemm3<<<nb_g, 256, 0, stream>>>(x, Wf, hp, N);
  k_agg<<<nb_node, 256, 0, stream>>>(hp, csr, rs, dinv, b, agg, N);
  k_lsm<<<nb_node, 256, 0, stream>>>(agg, z, N);
}